// Round 3
// baseline (366.724 us; speedup 1.0000x reference)
//
#include <hip/hip_runtime.h>
#include <hip/hip_bf16.h>
#include <math.h>

// Problem constants
#define CNUM   64
#define HH     192
#define WW     192
#define NBATCH 8
#define HWSZ   (HH * WW)                  // 36864
#define CHWSZ  (CNUM * HWSZ)              // 2359296
#define TOTALSZ ((size_t)NBATCH * CHWSZ)  // 18874368
#define QMAXF  127.0f
#define BNEPS  1e-5f
#define PW     194                        // padded spatial dim (1px zero border)
#define NTILES (3 * 48 * NBATCH)          // 1152 conv tiles (64px x 4rows)
#define NBLK   256                        // persistent conv blocks (1 per CU)

typedef __attribute__((ext_vector_type(8))) short bf16x8;
typedef __attribute__((ext_vector_type(4))) float f32x4;

// Workspace layout (float offsets)
#define OFF_PK1    0             // conv1 weights, B-frag swizzled bf16 (36864 shorts)
#define OFF_PK2    18432
#define OFF_STATS  36864         // sum1[256] ssq1[256] sum2[256] ssq2[256] wmax[2] = 1026 floats (memset 0)
#define OFF_SUM1   36864
#define OFF_SSQ1   37120
#define OFF_SUM2   37376
#define OFF_SSQ2   37632
#define OFF_WMAX   37888
#define OFF_SW     37890
// QA: q1 codes (padded swizzled NHWC); later reused as t2 (bf16 NCHW, smaller)
#define OFF_QA     38148
// QB: conv1 output values (padded swizzled NHWC bf16); conv2 transforms during staging
#define OFF_QB     (38148 + 9634816)

__device__ inline void gload16(const void* g, void* l) {
    __builtin_amdgcn_global_load_lds(
        (const __attribute__((address_space(1))) unsigned int*)g,
        (__attribute__((address_space(3))) unsigned int*)l, 16, 0, 0);
}
__device__ inline float bf2f(unsigned short u) {
    return __builtin_bit_cast(float, (unsigned)u << 16);
}
__device__ inline void tdec(int T, int& x0, int& y0, int& n) {
    const int xt = T % 3;
    const int r  = T / 3;
    const int yt = r % 48;
    n  = r / 48;
    x0 = xt * 64;
    y0 = yt * 4;
}

// ---------------------------------------------------------------------------
// Kernel 1a: weight absmax -> atomicMax on float bits (valid: values >= 0,
// accumulator memset to 0).  grid (18, 2), 8 elems/thread, float4 loads.
// ---------------------------------------------------------------------------
__global__ __launch_bounds__(256)
void wmax_kernel(const float* __restrict__ w1,
                 const float* __restrict__ w2,
                 unsigned* __restrict__ wmaxbits) {
    const int which = blockIdx.y;
    const float4* w4 = (const float4*)(which ? w2 : w1);
    const int b = (blockIdx.x * 256 + threadIdx.x) * 2;
    const float4 a = w4[b], c = w4[b + 1];
    float m = fmaxf(fmaxf(fmaxf(fabsf(a.x), fabsf(a.y)), fmaxf(fabsf(a.z), fabsf(a.w))),
                    fmaxf(fmaxf(fabsf(c.x), fabsf(c.y)), fmaxf(fabsf(c.z), fabsf(c.w))));
#pragma unroll
    for (int off = 1; off < 64; off <<= 1) m = fmaxf(m, __shfl_xor(m, off));
    if ((threadIdx.x & 63) == 0)
        atomicMax(wmaxbits + which, __builtin_bit_cast(unsigned, m));
}

// ---------------------------------------------------------------------------
// Kernel 1b: weight fake-quant -> INTEGER bf16, pre-swizzled into MFMA B-frag
// lane order: pk[(((t*2+icb)*4+ocb)*64+l)*8+j] = q(w[oc][ic][t]),
// oc=ocb*16+(l&15), ic=icb*32+((l>>4)&3)*8+j.  grid (18, 2).
// ---------------------------------------------------------------------------
__global__ __launch_bounds__(256)
void wpack_kernel(const float* __restrict__ w1,
                  const float* __restrict__ w2,
                  const unsigned* __restrict__ wmaxbits,
                  short* __restrict__ pk1,
                  short* __restrict__ pk2,
                  float* __restrict__ swout) {
    const int which = blockIdx.y;
    const float* w  = which ? w2 : w1;
    short*       pk = which ? pk2 : pk1;
    const float scale = __builtin_bit_cast(float, wmaxbits[which]) / QMAXF;
    if (blockIdx.x == 0 && threadIdx.x == 0) swout[which] = scale;
    const int i0 = (blockIdx.x * 256 + threadIdx.x) * 8;
#pragma unroll
    for (int k = 0; k < 8; ++k) {
        const int i = i0 + k;
        const int j   = i & 7;
        const int l   = (i >> 3) & 63;
        const int ocb = (i >> 9) & 3;
        const int icb = (i >> 11) & 1;
        const int t   = i >> 12;
        const int oc  = ocb * 16 + (l & 15);
        const int ic  = icb * 32 + ((l >> 4) & 3) * 8 + j;
        float q = rintf(w[oc * 576 + ic * 9 + t] / scale);
        q = fminf(fmaxf(q, -QMAXF), QMAXF);
        pk[i] = (short)(__builtin_bit_cast(unsigned, q) >> 16);  // exact integer bf16
    }
}

// ---------------------------------------------------------------------------
// Kernel 2: fp32 NCHW identity -> bf16 integer codes, zero-padded swizzled
// NHWC  q[n][py][px][slot], slot = icg ^ (px & 7), groups of 8 ch.
// grid (3, 194, 8), block 256.  Loads are float4 (16 B/lane, 4 in flight).
// ---------------------------------------------------------------------------
__global__ __launch_bounds__(256)
void requant_kernel(const float* __restrict__ inp,
                    const float* __restrict__ alpha_p,
                    short* __restrict__ q) {
    const int tid  = threadIdx.x;
    const int xblk = blockIdx.x;
    const int py   = blockIdx.y;
    const int n    = blockIdx.z;
    short* qrow = q + ((size_t)n * PW + py) * (PW * 64);

    if (py == 0 || py == PW - 1) {  // zero border rows
        for (int i = xblk * 256 + tid; i < PW * 64 * 2 / 16; i += 768)
            ((int4*)qrow)[i] = make_int4(0, 0, 0, 0);
        return;
    }
    if (xblk == 0 && tid < 8) ((int4*)qrow)[tid] = make_int4(0, 0, 0, 0);
    if (xblk == 2 && tid < 8) ((int4*)(qrow + 193 * 64))[tid] = make_int4(0, 0, 0, 0);

    const int gy = py - 1;
    const int x0 = xblk * 64;
    const float alpha  = alpha_p[0];
    const float inv_qs = QMAXF / alpha;

    __shared__ short s[64 * 72];  // [x][ic], stride 144B
    const int xq  = tid & 15;     // px quad
    const int icl = tid >> 4;     // 0..15

    // Batch the 4 float4 loads so they stay in flight together.
    float4 r[4];
#pragma unroll
    for (int p = 0; p < 4; ++p) {
        const int ic = icl * 4 + p;
        const size_t fo = ((size_t)n * CNUM + ic) * HWSZ + (size_t)gy * WW + x0 + xq * 4;
        r[p] = *(const float4*)(inp + fo);
    }
#pragma unroll
    for (int p = 0; p < 4; ++p) {
        const int ic = icl * 4 + p;
        float vv[4] = {r[p].x, r[p].y, r[p].z, r[p].w};
#pragma unroll
        for (int j = 0; j < 4; ++j) {
            float v = fminf(fmaxf(vv[j], -alpha), alpha);
            v = rintf(v * inv_qs);                    // integer in [-127,127]
            s[(xq * 4 + j) * 72 + ic] = (short)(__builtin_bit_cast(unsigned, v) >> 16);
        }
    }
    __syncthreads();
#pragma unroll
    for (int h = 0; h < 2; ++h) {
        const int t    = h * 256 + tid;
        const int xx   = t >> 3;
        const int slot = t & 7;
        const int px   = 1 + xblk * 64 + xx;
        const int g    = slot ^ (px & 7);
        const int4 val = *(const int4*)&s[xx * 72 + g * 8];
        *(int4*)(qrow + (size_t)px * 64 + slot * 8) = val;
    }
}

// ---------------------------------------------------------------------------
// Kernel 3/5: persistent double-buffered 3x3 conv via bf16 MFMA implicit GEMM.
// Grid 256 x 512thr (8 waves: wave = (row 0..3, oc-half)).  Each block owns
// tiles T = bid, bid+256, ... (4-5 tiles).  Pipeline per tile:
//   STAGE(next -> buf^1)  [issue only]  ;  COMPUTE(buf)  ;  (XFORM: transform
//   + ds_write next)  ;  epilogue stores+stats  ;  barrier  (vmcnt drain lands
//   AFTER ~2.3us of MFMA -> staging hidden).
// XFORM=1 (conv2): q holds bf16 VALUES; fold BN1 stats once, reg-stage with
//   affine+clamp+rint; borders forced to zero codes.
// SWZOUT=1 (conv1): store padded-swizzled NHWC bf16 values via LDS transpose.
// SWZOUT=0 (conv2): store bf16 NCHW.
// Stats: per-thread register accumulation, one atomic burst at kernel end.
// ---------------------------------------------------------------------------
template<int XFORM, int SWZOUT>
__global__ __launch_bounds__(512, 2)
void conv_mfma_kernel(const short* __restrict__ q,     // padded swizzled NHWC
                      const short* __restrict__ wpk,
                      const float* __restrict__ swp,   // weight scale
                      const float* __restrict__ alpha_p,
                      const float* __restrict__ slope_p,  // nullptr -> identity
                      const float* __restrict__ st_sum,   // XFORM: BN-in stats
                      const float* __restrict__ st_ssq,
                      const float* __restrict__ st_gamma,
                      const float* __restrict__ st_beta,
                      unsigned short* __restrict__ outp,  // bf16 NCHW (SWZOUT=0)
                      short* __restrict__ out_swz,        // padded NHWC (SWZOUT=1)
                      float* __restrict__ sum_g,          // 4 banks x 64
                      float* __restrict__ ssq_g) {
    __shared__ short s_in[2][6 * 66 * 64];          // 2 x 50688 B
    __shared__ short sT[SWZOUT ? 4 * 64 * 72 : 64]; // conv1 transpose buf (36864 B)
    __shared__ float sab[128];

    const int tid   = threadIdx.x;
    const int wave  = tid >> 6;
    const int lane  = tid & 63;
    const int xlane = lane & 15;
    const int icgl  = lane >> 4;
    const int row   = wave >> 1;   // output row within tile
    const int nbh   = wave & 1;    // oc half (0: oc 0..31, 1: oc 32..63)

    const float alpha  = alpha_p[0];
    const float inv_qs = QMAXF / alpha;
    const float sfin   = (alpha / QMAXF) * swp[0];
    const float slope  = slope_p ? slope_p[0] : 1.0f;

    if (XFORM) {
        if (tid < 64) {   // fold banked BN stats into per-channel affine (a,b)
            const float cnt = (float)(NBATCH * HWSZ);
            const float sm = st_sum[tid] + st_sum[64 + tid] + st_sum[128 + tid] + st_sum[192 + tid];
            const float sq = st_ssq[tid] + st_ssq[64 + tid] + st_ssq[128 + tid] + st_ssq[192 + tid];
            const float mean = sm / cnt;
            const float var  = sq / cnt - mean * mean;
            const float inv  = 1.0f / sqrtf(var + BNEPS);
            const float a = st_gamma[tid] * inv;
            sab[tid] = a;
            sab[64 + tid] = st_beta[tid] - mean * a;
        }
        __syncthreads();
    }

    float st_s[2]  = {0.f, 0.f};
    float st_ss[2] = {0.f, 0.f};

    // ---- prologue: stage first tile into buf 0
    {
        int x0, y0, n;
        tdec(blockIdx.x, x0, y0, n);
        const short* g0 = q + ((size_t)(n * PW + y0) * PW + x0) * 64;
        if (!XFORM) {
            for (int c = tid; c < 3168; c += 512) {
                const int r = c / 528;
                const int w = c - r * 528;
                gload16(g0 + (size_t)r * (PW * 64) + w * 8, &s_in[0][c * 8]);
            }
        } else {
#pragma unroll
            for (int k = 0; k < 7; ++k) {
                const int c = tid + k * 512;
                if (c < 3168) {
                    const int r  = c / 528;
                    const int w  = c - r * 528;
                    const int pxl = w >> 3, slot = w & 7;
                    const int px = x0 + pxl, py = y0 + r;
                    int4 val = make_int4(0, 0, 0, 0);
                    if ((unsigned)(px - 1) < 192u && (unsigned)(py - 1) < 192u) {
                        const int4 v = *(const int4*)(g0 + (size_t)r * (PW * 64) + w * 8);
                        const unsigned short* u = (const unsigned short*)&v;
                        const int gch = slot ^ (px & 7);
                        const float av[8] = {sab[gch*8+0], sab[gch*8+1], sab[gch*8+2], sab[gch*8+3],
                                             sab[gch*8+4], sab[gch*8+5], sab[gch*8+6], sab[gch*8+7]};
                        const float bv[8] = {sab[64+gch*8+0], sab[64+gch*8+1], sab[64+gch*8+2], sab[64+gch*8+3],
                                             sab[64+gch*8+4], sab[64+gch*8+5], sab[64+gch*8+6], sab[64+gch*8+7]};
                        unsigned wv[4];
#pragma unroll
                        for (int jj = 0; jj < 4; ++jj) {
                            float xx0 = av[jj*2]   * bf2f(u[jj*2])   + bv[jj*2];
                            float xx1 = av[jj*2+1] * bf2f(u[jj*2+1]) + bv[jj*2+1];
                            xx0 = fminf(fmaxf(xx0, -alpha), alpha);
                            xx1 = fminf(fmaxf(xx1, -alpha), alpha);
                            xx0 = rintf(xx0 * inv_qs);
                            xx1 = rintf(xx1 * inv_qs);
                            wv[jj] = (__builtin_bit_cast(unsigned, xx1) & 0xffff0000u) |
                                     (__builtin_bit_cast(unsigned, xx0) >> 16);
                        }
                        val = make_int4((int)wv[0], (int)wv[1], (int)wv[2], (int)wv[3]);
                    }
                    *(int4*)&s_in[0][c * 8] = val;
                }
            }
        }
    }
    __syncthreads();

    int cur = 0;
    for (int T = blockIdx.x; T < NTILES; T += NBLK) {
        int x0, y0, n;
        tdec(T, x0, y0, n);
        const int  Tn = T + NBLK;
        const bool hn = (Tn < NTILES);
        int nx0 = 0, ny0 = 0, nn2 = 0;
        if (hn) tdec(Tn, nx0, ny0, nn2);

        // ---- STAGE issue for next tile into buf^1
        int4 rg[7];
        if (hn) {
            const short* gn = q + ((size_t)(nn2 * PW + ny0) * PW + nx0) * 64;
            if (!XFORM) {
                for (int c = tid; c < 3168; c += 512) {
                    const int r = c / 528;
                    const int w = c - r * 528;
                    gload16(gn + (size_t)r * (PW * 64) + w * 8, &s_in[cur ^ 1][c * 8]);
                }
            } else {
#pragma unroll
                for (int k = 0; k < 7; ++k) {
                    const int c = tid + k * 512;
                    if (c < 3168) {
                        const int r = c / 528;
                        const int w = c - r * 528;
                        rg[k] = *(const int4*)(gn + (size_t)r * (PW * 64) + w * 8);
                    }
                }
            }
        }

        // ---- COMPUTE from buf[cur]
        const short* sbase = s_in[cur];
        f32x4 acc[4][2];
#pragma unroll
        for (int m = 0; m < 4; ++m)
#pragma unroll
            for (int j = 0; j < 2; ++j) acc[m][j] = (f32x4){0.f, 0.f, 0.f, 0.f};

#pragma unroll
        for (int t = 0; t < 9; ++t) {
            const int ky = t / 3, kx = t % 3;
            const int r = row + ky;
#pragma unroll
            for (int icb = 0; icb < 2; ++icb) {
                const int icg = icb * 4 + icgl;
                bf16x8 bfrag[2], afrag[4];
                const short* bp = wpk + (size_t)((t * 2 + icb) * 4 + nbh * 2) * 512 + lane * 8;
                bfrag[0] = *(const bf16x8*)(bp);
                bfrag[1] = *(const bf16x8*)(bp + 512);
#pragma unroll
                for (int m = 0; m < 4; ++m) {
                    const int x = m * 16 + xlane + kx;
                    afrag[m] = *(const bf16x8*)&sbase[(size_t)((r * 66 + x) * 8 + (icg ^ (x & 7))) * 8];
                }
#pragma unroll
                for (int m = 0; m < 4; ++m)
#pragma unroll
                    for (int j = 0; j < 2; ++j)
                        acc[m][j] = __builtin_amdgcn_mfma_f32_16x16x32_bf16(
                            afrag[m], bfrag[j], acc[m][j], 0, 0, 0);
            }
        }

        // ---- XFORM: transform + ds_write next tile (loads landed during MFMA)
        if (XFORM && hn) {
#pragma unroll
            for (int k = 0; k < 7; ++k) {
                const int c = tid + k * 512;
                if (c < 3168) {
                    const int r = c / 528;
                    const int w = c - r * 528;
                    const int pxl = w >> 3, slot = w & 7;
                    const int px = nx0 + pxl, py = ny0 + r;
                    int4 val = make_int4(0, 0, 0, 0);
                    if ((unsigned)(px - 1) < 192u && (unsigned)(py - 1) < 192u) {
                        const unsigned short* u = (const unsigned short*)&rg[k];
                        const int gch = slot ^ (px & 7);
                        const float av[8] = {sab[gch*8+0], sab[gch*8+1], sab[gch*8+2], sab[gch*8+3],
                                             sab[gch*8+4], sab[gch*8+5], sab[gch*8+6], sab[gch*8+7]};
                        const float bv[8] = {sab[64+gch*8+0], sab[64+gch*8+1], sab[64+gch*8+2], sab[64+gch*8+3],
                                             sab[64+gch*8+4], sab[64+gch*8+5], sab[64+gch*8+6], sab[64+gch*8+7]};
                        unsigned wv[4];
#pragma unroll
                        for (int jj = 0; jj < 4; ++jj) {
                            float xx0 = av[jj*2]   * bf2f(u[jj*2])   + bv[jj*2];
                            float xx1 = av[jj*2+1] * bf2f(u[jj*2+1]) + bv[jj*2+1];
                            xx0 = fminf(fmaxf(xx0, -alpha), alpha);
                            xx1 = fminf(fmaxf(xx1, -alpha), alpha);
                            xx0 = rintf(xx0 * inv_qs);
                            xx1 = rintf(xx1 * inv_qs);
                            wv[jj] = (__builtin_bit_cast(unsigned, xx1) & 0xffff0000u) |
                                     (__builtin_bit_cast(unsigned, xx0) >> 16);
                        }
                        val = make_int4((int)wv[0], (int)wv[1], (int)wv[2], (int)wv[3]);
                    }
                    *(int4*)&s_in[cur ^ 1][c * 8] = val;
                }
            }
        }

        // ---- epilogue: scale + prelu + stats accumulate + store
        const int gy  = y0 + row;
        const int gx0 = x0 + icgl * 4;
#pragma unroll
        for (int nb2 = 0; nb2 < 2; ++nb2) {
            const int oc = nbh * 32 + nb2 * 16 + xlane;
#pragma unroll
            for (int m = 0; m < 4; ++m) {
                float v[4];
#pragma unroll
                for (int rgi = 0; rgi < 4; ++rgi) {
                    float a = acc[m][nb2][rgi] * sfin;
                    a = (a >= 0.0f) ? a : slope * a;
                    v[rgi] = a;
                    st_s[nb2]  += a;
                    st_ss[nb2] += a * a;
                }
                if (SWZOUT) {
#pragma unroll
                    for (int rgi = 0; rgi < 4; ++rgi) {
                        const int pxl = m * 16 + icgl * 4 + rgi;
                        sT[row * (64 * 72) + pxl * 72 + oc] = (short)__builtin_bit_cast(
                            unsigned short, __float2bfloat16(v[rgi]));
                    }
                } else {
                    ushort4 pk;
                    pk.x = __builtin_bit_cast(unsigned short, __float2bfloat16(v[0]));
                    pk.y = __builtin_bit_cast(unsigned short, __float2bfloat16(v[1]));
                    pk.z = __builtin_bit_cast(unsigned short, __float2bfloat16(v[2]));
                    pk.w = __builtin_bit_cast(unsigned short, __float2bfloat16(v[3]));
                    *(ushort4*)&outp[(size_t)(n * CNUM + oc) * HWSZ + (size_t)gy * WW + gx0 + m * 16] = pk;
                }
            }
        }

        // barrier: buf[cur] reads done, next-tile DMA drained (after full MFMA
        // phase -> overlap achieved), sT / ds_writes visible
        __syncthreads();

        if (SWZOUT) {
            // coalesced int4 stores of this tile's rows from sT
            const int py = gy + 1;
            short* qrow = out_swz + ((size_t)n * PW + py) * (PW * 64);
#pragma unroll
            for (int kk = 0; kk < 4; ++kk) {
                const int idx  = (nbh * 4 + kk) * 64 + lane;
                const int xx   = idx >> 3;
                const int slot = idx & 7;
                const int px   = x0 + 1 + xx;
                const int g    = slot ^ (px & 7);
                *(int4*)(qrow + (size_t)px * 64 + slot * 8) =
                    *(const int4*)&sT[row * (64 * 72) + xx * 72 + g * 8];
            }
            __syncthreads();   // sT reads done before next tile overwrites
        }
        cur ^= 1;
    }

    // ---- final stats reduction + one atomic burst
#pragma unroll
    for (int nb2 = 0; nb2 < 2; ++nb2) {
        float s = st_s[nb2], ss = st_ss[nb2];
        s  += __shfl_xor(s, 16);  s  += __shfl_xor(s, 32);
        ss += __shfl_xor(ss, 16); ss += __shfl_xor(ss, 32);
        if (icgl == 0) {
            const int oc   = nbh * 32 + nb2 * 16 + xlane;
            const int bank = wave & 3;
            atomicAdd(sum_g + bank * 64 + oc, s);
            atomicAdd(ssq_g + bank * 64 + oc, ss);
        }
    }
}

// ---------------------------------------------------------------------------
// Kernel 6: out = identity*shortcut + bn2(t2[bf16]); BN2 stats folded per
// block; plus 3 scalar tails.  grid 4608, 4 float4/thread; each block's 1024
// float4s lie in ONE channel (1024 | 9216).
// ---------------------------------------------------------------------------
__global__ __launch_bounds__(256)
void final_kernel(const float* __restrict__ identity,
                  const unsigned short* __restrict__ t2,
                  const float* __restrict__ st_sum,
                  const float* __restrict__ st_ssq,
                  const float* __restrict__ st_gamma,
                  const float* __restrict__ st_beta,
                  const float* __restrict__ shortcut_p,
                  const float* __restrict__ bits,
                  const float* __restrict__ f,
                  const float* __restrict__ bits_out,
                  float* __restrict__ out) {
    __shared__ float sab[128];
    if (threadIdx.x < 64) {
        const int c = threadIdx.x;
        const float cnt = (float)(NBATCH * HWSZ);
        const float sm = st_sum[c] + st_sum[64 + c] + st_sum[128 + c] + st_sum[192 + c];
        const float sq = st_ssq[c] + st_ssq[64 + c] + st_ssq[128 + c] + st_ssq[192 + c];
        const float mean = sm / cnt;
        const float var  = sq / cnt - mean * mean;
        const float inv  = 1.0f / sqrtf(var + BNEPS);
        const float a = st_gamma[c] * inv;
        sab[c] = a;
        sab[64 + c] = st_beta[c] - mean * a;
    }
    __syncthreads();

    const size_t base = (size_t)blockIdx.x * 1024;
    const int   cch  = (int)((base / (HWSZ / 4)) % CNUM);   // uniform per block
    const float a  = sab[cch];
    const float bb = sab[64 + cch];
    const float sc = shortcut_p[0];

    float4  idv[4];
    ushort4 tv[4];
#pragma unroll
    for (int k = 0; k < 4; ++k) {
        const size_t i4 = base + (size_t)k * 256 + threadIdx.x;
        idv[k] = ((const float4*)identity)[i4];
        tv[k]  = ((const ushort4*)t2)[i4];
    }
#pragma unroll
    for (int k = 0; k < 4; ++k) {
        const size_t i4 = base + (size_t)k * 256 + threadIdx.x;
        float4 o;
        o.x = idv[k].x * sc + a * bf2f(tv[k].x) + bb;
        o.y = idv[k].y * sc + a * bf2f(tv[k].y) + bb;
        o.z = idv[k].z * sc + a * bf2f(tv[k].z) + bb;
        o.w = idv[k].w * sc + a * bf2f(tv[k].w) + bb;
        ((float4*)out)[i4] = o;
    }
    if (blockIdx.x == 0 && threadIdx.x == 0) {
        out[TOTALSZ + 0] = bits[0];
        out[TOTALSZ + 1] = f[0];
        out[TOTALSZ + 2] = bits_out[0];
    }
}

// ---------------------------------------------------------------------------
extern "C" void kernel_launch(void* const* d_in, const int* in_sizes, int n_in,
                              void* d_out, int out_size, void* d_ws, size_t ws_size,
                              hipStream_t stream) {
    const float* identity = (const float*)d_in[0];
    const float* bits     = (const float*)d_in[1];
    const float* f        = (const float*)d_in[2];
    const float* bits_out = (const float*)d_in[3];
    const float* w1       = (const float*)d_in[4];
    const float* w2       = (const float*)d_in[5];
    const float* alpha1   = (const float*)d_in[6];
    const float* alpha2   = (const float*)d_in[7];
    const float* gamma1   = (const float*)d_in[8];
    const float* beta1    = (const float*)d_in[9];
    const float* gamma2   = (const float*)d_in[10];
    const float* beta2    = (const float*)d_in[11];
    const float* prelu_a  = (const float*)d_in[12];
    const float* shortcut = (const float*)d_in[13];
    float* out = (float*)d_out;
    float* ws  = (float*)d_ws;

    short*    pk1   = (short*)(ws + OFF_PK1);
    short*    pk2   = (short*)(ws + OFF_PK2);
    float*    sum1  = ws + OFF_SUM1;
    float*    ssq1  = ws + OFF_SSQ1;
    float*    sum2  = ws + OFF_SUM2;
    float*    ssq2  = ws + OFF_SSQ2;
    unsigned* wmaxb = (unsigned*)(ws + OFF_WMAX);
    float*    sw    = ws + OFF_SW;
    short*          qa = (short*)(ws + OFF_QA);   // q1 codes; reused as t2 later
    short*          qb = (short*)(ws + OFF_QB);   // conv1 values (borders unwritten)
    unsigned short* t2 = (unsigned short*)(ws + OFF_QA);

    // 0. zero stats banks + wmax accumulators (graph-capturable memset node)
    hipMemsetAsync(ws + OFF_STATS, 0, 1026 * sizeof(float), stream);
    // 1a. weight absmax (parallel)
    hipLaunchKernelGGL(wmax_kernel, dim3(18, 2), dim3(256), 0, stream, w1, w2, wmaxb);
    // 2. identity -> q1 codes (independent of wmax; hides its tail)
    hipLaunchKernelGGL(requant_kernel, dim3(3, PW, NBATCH), dim3(256), 0, stream,
                       identity, alpha1, qa);
    // 1b. weight pack (parallel)
    hipLaunchKernelGGL(wpack_kernel, dim3(18, 2), dim3(256), 0, stream,
                       w1, w2, wmaxb, pk1, pk2, sw);
    // 3. conv1 + prelu -> qb (padded swizzled NHWC bf16 values) + stats1
    hipLaunchKernelGGL((conv_mfma_kernel<0, 1>), dim3(NBLK), dim3(512), 0, stream,
                       qa, pk1, sw + 0, alpha1, prelu_a,
                       (const float*)nullptr, (const float*)nullptr,
                       (const float*)nullptr, (const float*)nullptr,
                       (unsigned short*)nullptr, qb, sum1, ssq1);
    // 5. conv2: BN1-fold + requant during staging, -> t2 (bf16 NCHW) + stats2
    hipLaunchKernelGGL((conv_mfma_kernel<1, 0>), dim3(NBLK), dim3(512), 0, stream,
                       qb, pk2, sw + 1, alpha2, (const float*)nullptr,
                       sum1, ssq1, gamma1, beta1,
                       t2, (short*)nullptr, sum2, ssq2);
    // 6. residual + BN2 fold+apply + scalar tail
    hipLaunchKernelGGL(final_kernel, dim3((unsigned)(TOTALSZ / 4 / 1024)), dim3(256), 0, stream,
                       identity, t2, sum2, ssq2, gamma2, beta2,
                       shortcut, bits, f, bits_out, out);
}

// Round 4
// 247.371 us; speedup vs baseline: 1.4825x; 1.4825x over previous
//
#include <hip/hip_runtime.h>
#include <hip/hip_bf16.h>
#include <math.h>

// Problem constants
#define CNUM   64
#define HH     192
#define WW     192
#define NBATCH 8
#define HWSZ   (HH * WW)                  // 36864
#define CHWSZ  (CNUM * HWSZ)              // 2359296
#define TOTALSZ ((size_t)NBATCH * CHWSZ)  // 18874368
#define QMAXF  127.0f
#define BNEPS  1e-5f
#define PW     194                        // padded spatial dim (1px zero border)

typedef __attribute__((ext_vector_type(4))) int i32x4;

// Workspace layout (float offsets) — unchanged from round 2
#define OFF_PK1    0             // conv1 weights, i8 B-frag granules (36864 B)
#define OFF_PK2    18432
#define OFF_STATS  36864         // sum1[256] ssq1[256] sum2[256] ssq2[256] wmax[2]
#define OFF_SUM1   36864
#define OFF_SSQ1   37120
#define OFF_SUM2   37376
#define OFF_SSQ2   37632
#define OFF_WMAX   37888
#define OFF_SW     37890
// QA: q1 i8 codes (padded swizzle-4 NHWC, 19.3 MB); later reused as t2 (bf16 NCHW)
#define OFF_QA     38148
// QB: conv1 output values (padded swizzle-8 NHWC bf16, 38.5 MB)
#define OFF_QB     (38148 + 9634816)

__device__ inline void gload16(const void* g, void* l) {
    __builtin_amdgcn_global_load_lds(
        (const __attribute__((address_space(1))) unsigned int*)g,
        (__attribute__((address_space(3))) unsigned int*)l, 16, 0, 0);
}
__device__ inline float bf2f(unsigned short u) {
    return __builtin_bit_cast(float, (unsigned)u << 16);
}

// ---------------------------------------------------------------------------
// Kernel 1a: weight absmax -> atomicMax on float bits.  grid (18, 2).
// ---------------------------------------------------------------------------
__global__ __launch_bounds__(256)
void wmax_kernel(const float* __restrict__ w1,
                 const float* __restrict__ w2,
                 unsigned* __restrict__ wmaxbits) {
    const int which = blockIdx.y;
    const float4* w4 = (const float4*)(which ? w2 : w1);
    const int b = (blockIdx.x * 256 + threadIdx.x) * 2;
    const float4 a = w4[b], c = w4[b + 1];
    float m = fmaxf(fmaxf(fmaxf(fabsf(a.x), fabsf(a.y)), fmaxf(fabsf(a.z), fabsf(a.w))),
                    fmaxf(fmaxf(fabsf(c.x), fabsf(c.y)), fmaxf(fabsf(c.z), fabsf(c.w))));
#pragma unroll
    for (int off = 1; off < 64; off <<= 1) m = fmaxf(m, __shfl_xor(m, off));
    if ((threadIdx.x & 63) == 0)
        atomicMax(wmaxbits + which, __builtin_bit_cast(unsigned, m));
}

// ---------------------------------------------------------------------------
// Kernel 1b: weight fake-quant -> i8 codes, pre-swizzled into MFMA B-frag
// granules: pk[((t*4+ocb)*64+l)*16 + j] = q(w[oc][ic][t]),
// oc = ocb*16 + (l&15), ic = ((l>>4)&3)*16 + j.  grid (18, 2).
// ---------------------------------------------------------------------------
__global__ __launch_bounds__(256)
void wpack_kernel(const float* __restrict__ w1,
                  const float* __restrict__ w2,
                  const unsigned* __restrict__ wmaxbits,
                  char* __restrict__ pk1,
                  char* __restrict__ pk2,
                  float* __restrict__ swout) {
    const int which = blockIdx.y;
    const float* w  = which ? w2 : w1;
    char*        pk = which ? pk2 : pk1;
    const float scale = __builtin_bit_cast(float, wmaxbits[which]) / QMAXF;
    if (blockIdx.x == 0 && threadIdx.x == 0) swout[which] = scale;
    const int i0 = (blockIdx.x * 256 + threadIdx.x) * 8;
#pragma unroll
    for (int k = 0; k < 8; ++k) {
        const int i = i0 + k;
        const int j   = i & 15;
        const int l   = (i >> 4) & 63;
        const int ocb = (i >> 10) & 3;
        const int t   = i >> 12;
        const int oc  = ocb * 16 + (l & 15);
        const int ic  = ((l >> 4) & 3) * 16 + j;
        float q = rintf(w[oc * 576 + ic * 9 + t] / scale);
        q = fminf(fmaxf(q, -QMAXF), QMAXF);
        pk[i] = (char)(int)q;
    }
}

// ---------------------------------------------------------------------------
// Kernel 2: fp32 NCHW identity -> i8 codes, zero-padded swizzle-4 NHWC:
// q[n][py][px][g'] (16-ch granules, 16 B), g' = g16 ^ ((px>>1)&3).
// grid (3, 194, 8), block 256.
// ---------------------------------------------------------------------------
__global__ __launch_bounds__(256)
void requant_kernel(const float* __restrict__ inp,
                    const float* __restrict__ alpha_p,
                    char* __restrict__ q) {
    const int tid  = threadIdx.x;
    const int xblk = blockIdx.x;
    const int py   = blockIdx.y;
    const int n    = blockIdx.z;
    char* qrow = q + ((size_t)n * PW + py) * (PW * 64);   // 64 B per px

    if (py == 0 || py == PW - 1) {  // zero border rows (776 int4 per row)
        for (int i = xblk * 256 + tid; i < PW * 4; i += 768)
            ((int4*)qrow)[i] = make_int4(0, 0, 0, 0);
        return;
    }
    if (xblk == 0 && tid < 4) ((int4*)qrow)[tid] = make_int4(0, 0, 0, 0);
    if (xblk == 2 && tid < 4) ((int4*)(qrow + 193 * 64))[tid] = make_int4(0, 0, 0, 0);

    const int gy = py - 1;
    const int x0 = xblk * 64;
    const float alpha  = alpha_p[0];
    const float inv_qs = QMAXF / alpha;

    __shared__ short s[64 * 72];  // [x][ic] integer codes as shorts
    const int xq  = tid & 15;     // px quad
    const int icl = tid >> 4;     // 0..15 (4 ch each)

    float4 r[4];
#pragma unroll
    for (int p = 0; p < 4; ++p) {
        const int ic = icl * 4 + p;
        const size_t fo = ((size_t)n * CNUM + ic) * HWSZ + (size_t)gy * WW + x0 + xq * 4;
        r[p] = *(const float4*)(inp + fo);
    }
#pragma unroll
    for (int p = 0; p < 4; ++p) {
        const int ic = icl * 4 + p;
        float vv[4] = {r[p].x, r[p].y, r[p].z, r[p].w};
#pragma unroll
        for (int j = 0; j < 4; ++j) {
            float v = fminf(fmaxf(vv[j], -alpha), alpha);
            v = rintf(v * inv_qs);                    // integer in [-127,127]
            s[(xq * 4 + j) * 72 + ic] = (short)(int)v;
        }
    }
    __syncthreads();
    // output: one 16-ch granule per thread (64 px x 4 granules)
    {
        const int xx = tid >> 2;
        const int g  = tid & 3;
        const int px = 1 + x0 + xx;
        const int gp = g ^ ((px >> 1) & 3);
        const short* sp = &s[xx * 72 + g * 16];
        int4 val;
        char* vb = (char*)&val;
#pragma unroll
        for (int j = 0; j < 16; ++j) vb[j] = (char)sp[j];
        *(int4*)(qrow + (size_t)px * 64 + gp * 16) = val;
    }
}

// ---------------------------------------------------------------------------
// Kernel 3/5: 3x3 conv via i8 MFMA (16x16x64) implicit GEMM, round-2 one-shot
// block structure (grid 3x48x8, 256 thr, wave = output row).
// XFORM=0 (conv1): DMA-stage i8 code granules (q = qa, borders pre-zeroed).
// XFORM=1 (conv2): q = qb bf16 VALUES (swizzle-8); fold BN1 stats -> (a,b),
//   reg-transform (affine+clamp+rint -> i8) during staging; borders zeroed.
// SWZOUT=1 (conv1): store bf16 VALUES to qb (swizzle-8 NHWC) via 2-pass LDS
//   transpose (oc halves) to keep LDS <= 48.4 KB (3 blocks/CU).
// SWZOUT=0 (conv2): store bf16 NCHW.  Both: fused banked per-ch stats.
// ---------------------------------------------------------------------------
template<int XFORM, int SWZOUT>
__global__ __launch_bounds__(256, 3)
void conv_mfma_kernel(const char* __restrict__ q,
                      const char* __restrict__ wpk,
                      const float* __restrict__ swp,
                      const float* __restrict__ alpha_p,
                      const float* __restrict__ slope_p,   // nullptr -> identity
                      const float* __restrict__ st_sum,    // XFORM: BN-in stats
                      const float* __restrict__ st_ssq,
                      const float* __restrict__ st_gamma,
                      const float* __restrict__ st_beta,
                      unsigned short* __restrict__ outp,   // bf16 NCHW (SWZOUT=0)
                      unsigned short* __restrict__ out_swz,// qb bf16 NHWC (SWZOUT=1)
                      float* __restrict__ sum_g,
                      float* __restrict__ ssq_g) {
    __shared__ __align__(16) char s_in[1584 * 16];                  // 25344 B
    __shared__ __align__(16) short sT[SWZOUT ? 4 * 64 * 40 : 8];    // 20480 B (conv1)
    __shared__ float sred[256], ssred[256];
    __shared__ float sab[128];

    const int tid = threadIdx.x;
    const int x0 = blockIdx.x * 64;
    const int y0 = blockIdx.y * 4;
    const int n  = blockIdx.z;

    const float alpha  = alpha_p[0];
    const float inv_qs = QMAXF / alpha;

    if (XFORM) {
        if (tid < 64) {   // fold banked BN stats into per-channel affine (a,b)
            const float cnt = (float)(NBATCH * HWSZ);
            const float sm = st_sum[tid] + st_sum[64 + tid] + st_sum[128 + tid] + st_sum[192 + tid];
            const float sq = st_ssq[tid] + st_ssq[64 + tid] + st_ssq[128 + tid] + st_ssq[192 + tid];
            const float mean = sm / cnt;
            const float var  = sq / cnt - mean * mean;
            const float inv  = 1.0f / sqrtf(var + BNEPS);
            const float a = st_gamma[tid] * inv;
            sab[tid] = a;
            sab[64 + tid] = st_beta[tid] - mean * a;
        }
        __syncthreads();
        // reg-transform staging: 1584 granules (r, x, g'), 16 ch each
        const unsigned short* qv = (const unsigned short*)q;
        const unsigned short* qb0 = qv + ((size_t)(n * PW + y0) * PW + x0) * 64;
#pragma unroll
        for (int k = 0; k < 7; ++k) {
            const int c = tid + k * 256;
            if (c < 1584) {
                const int r  = c / 264;
                const int w  = c - r * 264;
                const int x  = w >> 2, gp = w & 3;
                const int px = x0 + x, pyy = y0 + r;
                int4 val = make_int4(0, 0, 0, 0);
                if ((unsigned)(px - 1) < 192u && (unsigned)(pyy - 1) < 192u) {
                    const int g16 = gp ^ ((x >> 1) & 3);
                    const unsigned short* qp = qb0 + (size_t)r * (PW * 64) + (size_t)x * 64;
                    const int s0 = (2 * g16) ^ (px & 7);
                    const int4 v0 = *(const int4*)(qp + s0 * 8);
                    const int4 v1 = *(const int4*)(qp + (s0 ^ 1) * 8);
                    const unsigned short* u0 = (const unsigned short*)&v0;
                    const unsigned short* u1 = (const unsigned short*)&v1;
                    char vb[16];
#pragma unroll
                    for (int jj = 0; jj < 8; ++jj) {
                        const int ic = g16 * 16 + jj;
                        float xx0 = sab[ic] * bf2f(u0[jj]) + sab[64 + ic];
                        xx0 = fminf(fmaxf(xx0, -alpha), alpha);
                        vb[jj] = (char)(int)rintf(xx0 * inv_qs);
                    }
#pragma unroll
                    for (int jj = 0; jj < 8; ++jj) {
                        const int ic = g16 * 16 + 8 + jj;
                        float xx1 = sab[ic] * bf2f(u1[jj]) + sab[64 + ic];
                        xx1 = fminf(fmaxf(xx1, -alpha), alpha);
                        vb[8 + jj] = (char)(int)rintf(xx1 * inv_qs);
                    }
                    val = *(int4*)vb;
                }
                *(int4*)&s_in[c * 16] = val;
            }
        }
    } else {
        // DMA staging: granule c -> (r, x, g'), always in-bounds (borders zeroed)
        const char* g0 = q + ((size_t)(n * PW + y0) * PW + x0) * 64;
        for (int c = tid; c < 1584; c += 256) {
            const int r = c / 264;
            const int w = c - r * 264;
            gload16(g0 + (size_t)r * (PW * 64) + w * 16, &s_in[c * 16]);
        }
    }
    __syncthreads();

    const int wave  = tid >> 6;    // output row within tile
    const int lane  = tid & 63;
    const int xlane = lane & 15;
    const int icgl  = lane >> 4;   // k-quadrant (16 ch)

    i32x4 acc[4][4];
#pragma unroll
    for (int m = 0; m < 4; ++m)
#pragma unroll
        for (int nb = 0; nb < 4; ++nb) acc[m][nb] = (i32x4){0, 0, 0, 0};

#pragma unroll
    for (int t = 0; t < 9; ++t) {
        const int ky = t / 3, kx = t % 3;
        const int r = wave + ky;
        i32x4 bfrag[4], afrag[4];
        const char* bp = wpk + ((size_t)(t * 4) * 64 + lane) * 16;
#pragma unroll
        for (int nb = 0; nb < 4; ++nb) bfrag[nb] = *(const i32x4*)(bp + (size_t)nb * 1024);
#pragma unroll
        for (int m = 0; m < 4; ++m) {
            const int x = m * 16 + xlane + kx;
            afrag[m] = *(const i32x4*)&s_in[(size_t)((r * 66 + x) * 4 + (icgl ^ ((x >> 1) & 3))) * 16];
        }
#pragma unroll
        for (int m = 0; m < 4; ++m)
#pragma unroll
            for (int nb = 0; nb < 4; ++nb)
                acc[m][nb] = __builtin_amdgcn_mfma_i32_16x16x64_i8(
                    afrag[m], bfrag[nb], acc[m][nb], 0, 0, 0);
    }

    // ---- epilogue: dequant scale + prelu + stats + store
    const float sfin  = (alpha / QMAXF) * swp[0];
    const float slope = slope_p ? slope_p[0] : 1.0f;
    const int gy  = y0 + wave;
    const int gx0 = x0 + icgl * 4;

    if (SWZOUT) {
        // 2-pass over oc halves through sT (4 rows x 64 px x 32 oc, stride 40)
#pragma unroll
        for (int h = 0; h < 2; ++h) {
#pragma unroll
            for (int nbi = 0; nbi < 2; ++nbi) {
                const int nb = 2 * h + nbi;
                const int oc = nb * 16 + xlane;
                float s = 0.0f, ss = 0.0f;
#pragma unroll
                for (int m = 0; m < 4; ++m) {
#pragma unroll
                    for (int rgi = 0; rgi < 4; ++rgi) {
                        float a = (float)acc[m][nb][rgi] * sfin;
                        a = (a >= 0.0f) ? a : slope * a;
                        s += a;
                        ss += a * a;
                        const int pxl = m * 16 + icgl * 4 + rgi;
                        sT[(wave * 64 + pxl) * 40 + (nbi * 16 + xlane)] =
                            (short)__builtin_bit_cast(unsigned short, __float2bfloat16(a));
                    }
                }
                s  += __shfl_xor(s, 16);  s  += __shfl_xor(s, 32);
                ss += __shfl_xor(ss, 16); ss += __shfl_xor(ss, 32);
                if (icgl == 0) { sred[wave * 64 + oc] = s; ssred[wave * 64 + oc] = ss; }
            }
            __syncthreads();   // sT half visible
            {
                const int py = gy + 1;
                unsigned short* qrow = out_swz + ((size_t)n * PW + py) * (PW * 64);
#pragma unroll
                for (int kk = 0; kk < 4; ++kk) {
                    const int idx = kk * 64 + lane;
                    const int xx  = idx >> 2;
                    const int gg  = idx & 3;
                    const int g8  = h * 4 + gg;
                    const int px  = x0 + 1 + xx;
                    const int slot = g8 ^ (px & 7);
                    *(int4*)(qrow + (size_t)px * 64 + slot * 8) =
                        *(const int4*)&sT[(wave * 64 + xx) * 40 + gg * 8];
                }
            }
            __syncthreads();   // sT reads done before half 1 overwrites
        }
    } else {
#pragma unroll
        for (int nb = 0; nb < 4; ++nb) {
            const int oc = nb * 16 + xlane;
            float s = 0.0f, ss = 0.0f;
#pragma unroll
            for (int m = 0; m < 4; ++m) {
                float v[4];
#pragma unroll
                for (int rgi = 0; rgi < 4; ++rgi) {
                    float a = (float)acc[m][nb][rgi] * sfin;
                    a = (a >= 0.0f) ? a : slope * a;
                    v[rgi] = a;
                    s += a;
                    ss += a * a;
                }
                ushort4 pk;
                pk.x = __builtin_bit_cast(unsigned short, __float2bfloat16(v[0]));
                pk.y = __builtin_bit_cast(unsigned short, __float2bfloat16(v[1]));
                pk.z = __builtin_bit_cast(unsigned short, __float2bfloat16(v[2]));
                pk.w = __builtin_bit_cast(unsigned short, __float2bfloat16(v[3]));
                *(ushort4*)&outp[(size_t)(n * CNUM + oc) * HWSZ + (size_t)gy * WW + gx0 + m * 16] = pk;
            }
            s  += __shfl_xor(s, 16);  s  += __shfl_xor(s, 32);
            ss += __shfl_xor(ss, 16); ss += __shfl_xor(ss, 32);
            if (icgl == 0) { sred[wave * 64 + oc] = s; ssred[wave * 64 + oc] = ss; }
        }
        __syncthreads();
    }

    const int bank = (blockIdx.y ^ blockIdx.z) & 3;
    if (tid < 64) {
        atomicAdd(sum_g + bank * 64 + tid,
                  sred[tid] + sred[64 + tid] + sred[128 + tid] + sred[192 + tid]);
    } else if (tid < 128) {
        const int c = tid - 64;
        atomicAdd(ssq_g + bank * 64 + c,
                  ssred[c] + ssred[64 + c] + ssred[128 + c] + ssred[192 + c]);
    }
}

// ---------------------------------------------------------------------------
// Kernel 6: out = identity*shortcut + bn2(t2[bf16]); BN2 stats folded per
// block; plus 3 scalar tails.  grid 4608, 4 float4/thread.
// ---------------------------------------------------------------------------
__global__ __launch_bounds__(256)
void final_kernel(const float* __restrict__ identity,
                  const unsigned short* __restrict__ t2,
                  const float* __restrict__ st_sum,
                  const float* __restrict__ st_ssq,
                  const float* __restrict__ st_gamma,
                  const float* __restrict__ st_beta,
                  const float* __restrict__ shortcut_p,
                  const float* __restrict__ bits,
                  const float* __restrict__ f,
                  const float* __restrict__ bits_out,
                  float* __restrict__ out) {
    __shared__ float sab[128];
    if (threadIdx.x < 64) {
        const int c = threadIdx.x;
        const float cnt = (float)(NBATCH * HWSZ);
        const float sm = st_sum[c] + st_sum[64 + c] + st_sum[128 + c] + st_sum[192 + c];
        const float sq = st_ssq[c] + st_ssq[64 + c] + st_ssq[128 + c] + st_ssq[192 + c];
        const float mean = sm / cnt;
        const float var  = sq / cnt - mean * mean;
        const float inv  = 1.0f / sqrtf(var + BNEPS);
        const float a = st_gamma[c] * inv;
        sab[c] = a;
        sab[64 + c] = st_beta[c] - mean * a;
    }
    __syncthreads();

    const size_t base = (size_t)blockIdx.x * 1024;
    const int   cch  = (int)((base / (HWSZ / 4)) % CNUM);   // uniform per block
    const float a  = sab[cch];
    const float bb = sab[64 + cch];
    const float sc = shortcut_p[0];

    float4  idv[4];
    ushort4 tv[4];
#pragma unroll
    for (int k = 0; k < 4; ++k) {
        const size_t i4 = base + (size_t)k * 256 + threadIdx.x;
        idv[k] = ((const float4*)identity)[i4];
        tv[k]  = ((const ushort4*)t2)[i4];
    }
#pragma unroll
    for (int k = 0; k < 4; ++k) {
        const size_t i4 = base + (size_t)k * 256 + threadIdx.x;
        float4 o;
        o.x = idv[k].x * sc + a * bf2f(tv[k].x) + bb;
        o.y = idv[k].y * sc + a * bf2f(tv[k].y) + bb;
        o.z = idv[k].z * sc + a * bf2f(tv[k].z) + bb;
        o.w = idv[k].w * sc + a * bf2f(tv[k].w) + bb;
        ((float4*)out)[i4] = o;
    }
    if (blockIdx.x == 0 && threadIdx.x == 0) {
        out[TOTALSZ + 0] = bits[0];
        out[TOTALSZ + 1] = f[0];
        out[TOTALSZ + 2] = bits_out[0];
    }
}

// ---------------------------------------------------------------------------
extern "C" void kernel_launch(void* const* d_in, const int* in_sizes, int n_in,
                              void* d_out, int out_size, void* d_ws, size_t ws_size,
                              hipStream_t stream) {
    const float* identity = (const float*)d_in[0];
    const float* bits     = (const float*)d_in[1];
    const float* f        = (const float*)d_in[2];
    const float* bits_out = (const float*)d_in[3];
    const float* w1       = (const float*)d_in[4];
    const float* w2       = (const float*)d_in[5];
    const float* alpha1   = (const float*)d_in[6];
    const float* alpha2   = (const float*)d_in[7];
    const float* gamma1   = (const float*)d_in[8];
    const float* beta1    = (const float*)d_in[9];
    const float* gamma2   = (const float*)d_in[10];
    const float* beta2    = (const float*)d_in[11];
    const float* prelu_a  = (const float*)d_in[12];
    const float* shortcut = (const float*)d_in[13];
    float* out = (float*)d_out;
    float* ws  = (float*)d_ws;

    char*     pk1   = (char*)(ws + OFF_PK1);
    char*     pk2   = (char*)(ws + OFF_PK2);
    float*    sum1  = ws + OFF_SUM1;
    float*    ssq1  = ws + OFF_SSQ1;
    float*    sum2  = ws + OFF_SUM2;
    float*    ssq2  = ws + OFF_SSQ2;
    unsigned* wmaxb = (unsigned*)(ws + OFF_WMAX);
    float*    sw    = ws + OFF_SW;
    char*           qa = (char*)(ws + OFF_QA);            // i8 codes; reused as t2
    unsigned short* qb = (unsigned short*)(ws + OFF_QB);  // conv1 bf16 values
    unsigned short* t2 = (unsigned short*)(ws + OFF_QA);

    // 0. zero stats banks + wmax accumulators
    hipMemsetAsync(ws + OFF_STATS, 0, 1026 * sizeof(float), stream);
    // 1a. weight absmax
    hipLaunchKernelGGL(wmax_kernel, dim3(18, 2), dim3(256), 0, stream, w1, w2, wmaxb);
    // 2. identity -> q1 i8 codes
    hipLaunchKernelGGL(requant_kernel, dim3(3, PW, NBATCH), dim3(256), 0, stream,
                       identity, alpha1, qa);
    // 1b. weight pack (i8)
    hipLaunchKernelGGL(wpack_kernel, dim3(18, 2), dim3(256), 0, stream,
                       w1, w2, wmaxb, pk1, pk2, sw);
    // 3. conv1 + prelu -> qb (bf16 swizzle-8 NHWC values) + stats1
    hipLaunchKernelGGL((conv_mfma_kernel<0, 1>), dim3(3, HH / 4, NBATCH), dim3(256), 0, stream,
                       qa, pk1, sw + 0, alpha1, prelu_a,
                       (const float*)nullptr, (const float*)nullptr,
                       (const float*)nullptr, (const float*)nullptr,
                       (unsigned short*)nullptr, qb, sum1, ssq1);
    // 5. conv2: BN1-fold + requant(i8) during staging -> t2 (bf16 NCHW) + stats2
    hipLaunchKernelGGL((conv_mfma_kernel<1, 0>), dim3(3, HH / 4, NBATCH), dim3(256), 0, stream,
                       (const char*)qb, pk2, sw + 1, alpha2, (const float*)nullptr,
                       sum1, ssq1, gamma1, beta1,
                       t2, (unsigned short*)nullptr, sum2, ssq2);
    // 6. residual + BN2 fold+apply + scalar tail
    hipLaunchKernelGGL(final_kernel, dim3((unsigned)(TOTALSZ / 4 / 1024)), dim3(256), 0, stream,
                       identity, t2, sum2, ssq2, gamma2, beta2,
                       shortcut, bits, f, bits_out, out);
}